// Round 7
// baseline (1226.294 us; speedup 1.0000x reference)
//
#include <hip/hip_runtime.h>
#include <cstdint>

#define NCLS 60
#define KC 512
#define DD 256
#define BB 32
#define NP 4096
#define CPAD 68   // cs row stride (floats): 2-way bank alias on reads = free
#define ZROW 128  // zs_d row stride (floats) = n-tile width, read2st64-friendly
#define LDP 260   // row stride for the sq kernels

typedef float v2f __attribute__((ext_vector_type(2)));

// Packed fp32 mul/add: lo/hi lanes are IEEE RN f32, bit-identical to scalar
// v_mul_f32/v_add_f32. asm is opaque to the compiler -> no fma contraction.
__device__ __forceinline__ v2f pk_mul(v2f a, v2f b) {
  v2f d;
  asm("v_pk_mul_f32 %0, %1, %2" : "=v"(d) : "v"(a), "v"(b));
  return d;
}
__device__ __forceinline__ v2f pk_add(v2f a, v2f b) {
  v2f d;
  asm("v_pk_add_f32 %0, %1, %2" : "=v"(d) : "v"(a), "v"(b));
  return d;
}

// Rounded fp32 multiply that cannot be fused into a following add.
__device__ __forceinline__ float mul_rn_nofuse(float a, float b) {
  float p = a * b;
  asm("" : "+v"(p));
  return p;
}

// numpy pairwise_sum of x*x over 256 contiguous floats.
__device__ __forceinline__ float np_pairwise256_sq(const float* row) {
  float h0 = 0.f, h1 = 0.f;
#pragma unroll
  for (int half = 0; half < 2; ++half) {
    const float* a = row + half * 128;
    float r[8];
#pragma unroll
    for (int j = 0; j < 8; ++j) r[j] = mul_rn_nofuse(a[j], a[j]);
    for (int blk = 1; blk < 16; ++blk) {
#pragma unroll
      for (int j = 0; j < 8; ++j) {
        float p = mul_rn_nofuse(a[blk * 8 + j], a[blk * 8 + j]);
        r[j] = r[j] + p;
      }
    }
    float res = ((r[0] + r[1]) + (r[2] + r[3])) + ((r[4] + r[5]) + (r[6] + r[7]));
    if (half == 0) h0 = res; else h1 = res;
  }
  return h0 + h1;
}

__global__ __launch_bounds__(64) void zsq_kernel(const float* __restrict__ z,
                                                 float* __restrict__ zsq) {
  __shared__ float zs[64][LDP];
  int t = threadIdx.x;
  int b = blockIdx.x >> 6;
  int n0 = (blockIdx.x & 63) * 64;
  const float* zb = z + (size_t)b * DD * NP;
  for (int d = 0; d < DD; ++d) zs[t][d] = zb[(size_t)d * NP + n0 + t];
  __syncthreads();
  zsq[b * NP + n0 + t] = np_pairwise256_sq(&zs[t][0]);
}

__global__ __launch_bounds__(64) void cbsq_kernel(const float* __restrict__ emb,
                                                  float* __restrict__ cbsq) {
  __shared__ float cs[64][LDP];
  int t = threadIdx.x;
  int r0 = blockIdx.x * 64;
  const float4* e4 = (const float4*)emb;
  for (int rr = 0; rr < 64; ++rr) {
    float4 v = e4[(size_t)(r0 + rr) * 64 + t];
    *(float4*)&cs[rr][t * 4] = v;
  }
  __syncthreads();
  cbsq[r0 + t] = np_pairwise256_sq(&cs[t][0]);
}

// ---- main: 8x4 micro-tile, packed-fp32, np-einsum SSE chain order ----
// Z in native [d][n] LDS layout (conflict-free staging, z-pair reads via
// ds_read2st64). C in [k][d] rows padded to 68 (b128 reads, 2-way = free).
// launch_bounds(256,1): un-cap the allocator — (256,2) empirically pins VGPR
// at 128 and spills the 8x4 accumulator set (rounds 4/6: 150 MB scratch).
__global__ __launch_bounds__(256, 1) void vq_main_kernel(
    const float* __restrict__ z, const int* __restrict__ c,
    const float* __restrict__ emb, const float* __restrict__ zsq,
    const float* __restrict__ cbsq, int* __restrict__ idx_out) {
  __shared__ __align__(16) float zs_d[64][ZROW];  // [d_local][n] — 32 KB
  __shared__ __align__(16) float cs[64][CPAD];    // [k_local][d_local] — 17 KB
  const int t = threadIdx.x;
  const int b = blockIdx.y;
  const int n0 = blockIdx.x * 128;
  const int tn = t >> 4, tk = t & 15;
  const int cls = c[b];
  const float* __restrict__ zb = z + (size_t)b * DD * NP;
  const float* __restrict__ cb = emb + (size_t)cls * KC * DD;
  const float* __restrict__ cbsqb = cbsq + cls * KC;

  float zsqv[8];
#pragma unroll
  for (int i = 0; i < 8; ++i) zsqv[i] = zsq[b * NP + n0 + tn + 16 * i];

  float m[8];
  int bi[8];
#pragma unroll
  for (int i = 0; i < 8; ++i) { m[i] = 3.4e38f; bi[i] = 0; }

#pragma unroll 1
  for (int kt = 0; kt < 8; ++kt) {
    const float* __restrict__ cbk = cb + (size_t)kt * 64 * DD;
    v2f A[8][4][2];
#pragma unroll
    for (int i = 0; i < 8; ++i)
#pragma unroll
      for (int j = 0; j < 4; ++j) {
        A[i][j][0] = (v2f){0.f, 0.f};
        A[i][j][1] = (v2f){0.f, 0.f};
      }

#pragma unroll 1
    for (int dc = 0; dc < 4; ++dc) {
      const int d0g = dc * 64;
      __syncthreads();  // previous chunk fully consumed
      // stage z chunk [64 d][128 n], native layout: b128 in, b128 out (0-conflict)
#pragma unroll
      for (int it = 0; it < 8; ++it) {
        int flat = it * 256 + t;
        int d = flat >> 5, n4 = flat & 31;
        *(float4*)&zs_d[d][n4 * 4] =
            *(const float4*)&zb[(size_t)(d0g + d) * NP + n0 + n4 * 4];
      }
      // stage cb chunk [64 k][64 d]: straight copy, conflict-free.
#pragma unroll
      for (int it = 0; it < 4; ++it) {
        int flat = it * 256 + t;
        int kr = flat >> 4, dq = flat & 15;
        *(float4*)&cs[kr][dq * 4] =
            *(const float4*)&cbk[(size_t)kr * DD + d0g + dq * 4];
      }
      __syncthreads();

#pragma unroll 1
      for (int t16 = 0; t16 < 4; ++t16) {
#pragma unroll
        for (int s = 3; s >= 0; --s) {
          const int d0 = t16 * 16 + s * 4;
          // c operands: one b128 per k-row; v2f halves used in place
          float4 cf[4];
#pragma unroll
          for (int j = 0; j < 4; ++j) cf[j] = *(const float4*)&cs[tk + 16 * j][d0];
#pragma unroll
          for (int i = 0; i < 8; ++i) {
            const int ni = tn + 16 * i;
            // (z[d][ni], z[d+1][ni]): 512B-apart pair -> ds_read2st64; broadcast
            v2f zp0 = {zs_d[d0][ni], zs_d[d0 + 1][ni]};
            v2f zp1 = {zs_d[d0 + 2][ni], zs_d[d0 + 3][ni]};
#pragma unroll
            for (int j = 0; j < 4; ++j) {
              const v2f* cp = (const v2f*)&cf[j];
              A[i][j][0] = pk_add(pk_mul(zp0, cp[0]), A[i][j][0]);
              A[i][j][1] = pk_add(pk_mul(zp1, cp[1]), A[i][j][1]);
            }
          }
        }
      }
    }

    // npyv hadd + dist + first-min update (k strictly ascending per thread)
#pragma unroll
    for (int j = 0; j < 4; ++j) {
      const int k = kt * 64 + tk + 16 * j;
      const float cq = cbsqb[k];
#pragma unroll
      for (int i = 0; i < 8; ++i) {
        float dot = (A[i][j][0].x + A[i][j][0].y) + (A[i][j][1].x + A[i][j][1].y);
        float dist = (zsqv[i] - 2.0f * dot) + cq;  // 2*dot exact (pow2 mul)
        if (dist < m[i]) { m[i] = dist; bi[i] = k; }
      }
    }
  }

  // lex-min (value, index) across the 16 tk-lanes sharing each n
#pragma unroll
  for (int i = 0; i < 8; ++i) {
#pragma unroll
    for (int off = 8; off >= 1; off >>= 1) {
      float om = __shfl_xor(m[i], off);
      int oi = __shfl_xor(bi[i], off);
      if (om < m[i] || (om == m[i] && oi < bi[i])) { m[i] = om; bi[i] = oi; }
    }
  }
  if (tk == 0) {
#pragma unroll
    for (int i = 0; i < 8; ++i) idx_out[b * NP + n0 + tn + 16 * i] = bi[i];
  }
}

// ---- gather selected rows -> [B,H,W,D] (bitwise copy of embedding rows) ----
__global__ __launch_bounds__(256) void vq_gather_kernel(
    const int* __restrict__ c, const float* __restrict__ emb,
    const int* __restrict__ idx, float* __restrict__ out) {
  int t = threadIdx.x;
  int r = blockIdx.x * 4 + (t >> 6);
  int lane = t & 63;
  int b = r >> 12;
  int k = idx[r];
  const float4* src = (const float4*)(emb + (size_t)(c[b] * KC + k) * DD);
  float4* dst = (float4*)(out + (size_t)r * DD);
  dst[lane] = src[lane];
}

extern "C" void kernel_launch(void* const* d_in, const int* in_sizes, int n_in,
                              void* d_out, int out_size, void* d_ws, size_t ws_size,
                              hipStream_t stream) {
  const float* z = (const float*)d_in[0];    // [32,256,64,64]
  const int* c = (const int*)d_in[1];        // [32]
  const float* emb = (const float*)d_in[2];  // [30720,256]
  float* out = (float*)d_out;                // [32,64,64,256]

  char* ws = (char*)d_ws;
  float* zsq = (float*)ws;                       // 131072 f32
  float* cbsq = (float*)(ws + 524288);           // 30720 f32
  int* idx = (int*)(ws + 524288 + 122880);       // 131072 i32

  zsq_kernel<<<BB * (NP / 64), 64, 0, stream>>>(z, zsq);
  cbsq_kernel<<<(NCLS * KC) / 64, 64, 0, stream>>>(emb, cbsq);
  dim3 gA(NP / 128, BB);
  vq_main_kernel<<<gA, 256, 0, stream>>>(z, c, emb, zsq, cbsq, idx);
  vq_gather_kernel<<<(BB * NP) / 4, 256, 0, stream>>>(c, emb, idx, out);
}

// Round 8
// 909.516 us; speedup vs baseline: 1.3483x; 1.3483x over previous
//
#include <hip/hip_runtime.h>
#include <cstdint>

#define NCLS 60
#define KC 512
#define DD 256
#define BB 32
#define NP 4096
#define DPAD 68   // LDS row stride (floats): mult-of-4 for b128; conflict-analyzed
#define LDP 260   // row stride for the prep kernels

typedef float v2f __attribute__((ext_vector_type(2)));

// Packed fp32 mul / in-place add: lanes are IEEE RN f32, bit-identical to
// scalar v_mul_f32/v_add_f32. asm is opaque -> no fma contraction; "+v" on the
// accumulator guarantees in-place add (no register-copy inflation).
__device__ __forceinline__ v2f pk_mul(v2f a, v2f b) {
  v2f d;
  asm("v_pk_mul_f32 %0, %1, %2" : "=v"(d) : "v"(a), "v"(b));
  return d;
}
__device__ __forceinline__ void pk_acc(v2f& a, v2f p) {
  asm("v_pk_add_f32 %0, %1, %0" : "+v"(a) : "v"(p));  // a = p + a
}

// Rounded fp32 multiply that cannot fuse into a following add.
__device__ __forceinline__ float mul_rn_nofuse(float a, float b) {
  float p = a * b;
  asm("" : "+v"(p));
  return p;
}

// numpy pairwise_sum of x*x over 256 contiguous floats.
__device__ __forceinline__ float np_pairwise256_sq(const float* row) {
  float h0 = 0.f, h1 = 0.f;
#pragma unroll
  for (int half = 0; half < 2; ++half) {
    const float* a = row + half * 128;
    float r[8];
#pragma unroll
    for (int j = 0; j < 8; ++j) r[j] = mul_rn_nofuse(a[j], a[j]);
    for (int blk = 1; blk < 16; ++blk) {
#pragma unroll
      for (int j = 0; j < 8; ++j) {
        float p = mul_rn_nofuse(a[blk * 8 + j], a[blk * 8 + j]);
        r[j] = r[j] + p;
      }
    }
    float res = ((r[0] + r[1]) + (r[2] + r[3])) + ((r[4] + r[5]) + (r[6] + r[7]));
    if (half == 0) h0 = res; else h1 = res;
  }
  return h0 + h1;
}

// ---- prep: z_sq (numpy order) AND global transpose zT[b][n][d] (into d_out) --
__global__ __launch_bounds__(64) void zprep_kernel(const float* __restrict__ z,
                                                   float* __restrict__ zsq,
                                                   float* __restrict__ zT) {
  __shared__ float zs[64][LDP];
  int t = threadIdx.x;
  int b = blockIdx.x >> 6;
  int n0 = (blockIdx.x & 63) * 64;
  const float* zb = z + (size_t)b * DD * NP;
  for (int d = 0; d < DD; ++d) zs[t][d] = zb[(size_t)d * NP + n0 + t];
  __syncthreads();
  zsq[b * NP + n0 + t] = np_pairwise256_sq(&zs[t][0]);
  // write zT rows coalesced: per it, 64 lanes cover one full 1KB row
  float* ob = zT + ((size_t)b * NP + n0) * DD;
  for (int it = 0; it < 64; ++it) {
    *(float4*)&ob[(size_t)it * DD + t * 4] = *(const float4*)&zs[it][t * 4];
  }
}

__global__ __launch_bounds__(64) void cbsq_kernel(const float* __restrict__ emb,
                                                  float* __restrict__ cbsq) {
  __shared__ float cs[64][LDP];
  int t = threadIdx.x;
  int r0 = blockIdx.x * 64;
  const float4* e4 = (const float4*)emb;
  for (int rr = 0; rr < 64; ++rr) {
    float4 v = e4[(size_t)(r0 + rr) * 64 + t];
    *(float4*)&cs[rr][t * 4] = v;
  }
  __syncthreads();
  cbsq[r0 + t] = np_pairwise256_sq(&cs[t][0]);
}

// ---- main: 8n x 4k micro-tile, packed-fp32, np-einsum SSE chain order ----
// zT staged b128->b128 into zs[n][d] (natural (d,d+1) pairs; reads are
// 16-lane broadcast). cs[k][d] straight copy (2-way alias = free).
// Default launch_bounds(256): LDS 52 KB -> 3 blocks/CU -> VGPR budget ~170.
// kt split across gridDim.z; exact first-min merged via order-preserving
// packed atomicMin (key = sign-flipped dist bits, low = index).
__global__ __launch_bounds__(256) void vq_main_kernel(
    const float* __restrict__ zT, const int* __restrict__ c,
    const float* __restrict__ emb, const float* __restrict__ zsq,
    const float* __restrict__ cbsq, unsigned long long* __restrict__ best) {
  __shared__ __align__(16) float zs[128][DPAD];  // 34.8 KB
  __shared__ __align__(16) float cs[64][DPAD];   // 17.4 KB
  const int t = threadIdx.x;
  const int b = blockIdx.y;
  const int n0 = blockIdx.x * 128;
  const int kt0 = blockIdx.z * 4;
  const int tn = t >> 4, tk = t & 15;
  const int cls = c[b];
  const float* __restrict__ zTb = zT + ((size_t)b * NP + n0) * DD;
  const float* __restrict__ cbc = emb + (size_t)cls * KC * DD;
  const float* __restrict__ cbsqb = cbsq + cls * KC;

  float zsqv[8];
#pragma unroll
  for (int i = 0; i < 8; ++i) zsqv[i] = zsq[b * NP + n0 + tn + 16 * i];

  float m[8];
  int bi[8];
#pragma unroll
  for (int i = 0; i < 8; ++i) { m[i] = 3.4e38f; bi[i] = 0; }

#pragma unroll 1
  for (int ktt = 0; ktt < 4; ++ktt) {
    const int kt = kt0 + ktt;
    const float* __restrict__ cbk = cbc + (size_t)kt * 64 * DD;
    v2f A[8][4][2];
#pragma unroll
    for (int i = 0; i < 8; ++i)
#pragma unroll
      for (int j = 0; j < 4; ++j) {
        A[i][j][0] = (v2f){0.f, 0.f};
        A[i][j][1] = (v2f){0.f, 0.f};
      }

#pragma unroll 1
    for (int dc = 0; dc < 4; ++dc) {
      const int d0g = dc * 64;
      __syncthreads();  // previous chunk fully consumed
      // stage z [128 n][64 d] from zT: b128 both sides, conflict-free
#pragma unroll
      for (int it = 0; it < 8; ++it) {
        int f4i = it * 256 + t;
        int row = f4i >> 4, dq = f4i & 15;
        *(float4*)&zs[row][dq * 4] =
            *(const float4*)&zTb[(size_t)row * DD + d0g + dq * 4];
      }
      // stage c [64 k][64 d]: straight copy, conflict-free
#pragma unroll
      for (int it = 0; it < 4; ++it) {
        int f4i = it * 256 + t;
        int kr = f4i >> 4, dq = f4i & 15;
        *(float4*)&cs[kr][dq * 4] =
            *(const float4*)&cbk[(size_t)kr * DD + d0g + dq * 4];
      }
      __syncthreads();

#pragma unroll 1
      for (int t16 = 0; t16 < 4; ++t16) {
#pragma unroll
        for (int s = 3; s >= 0; --s) {
          const int d0 = t16 * 16 + s * 4;
          float4 cf[4];
#pragma unroll
          for (int j = 0; j < 4; ++j) cf[j] = *(const float4*)&cs[tk + 16 * j][d0];
#pragma unroll
          for (int i = 0; i < 8; ++i) {
            float4 zf = *(const float4*)&zs[tn + 16 * i][d0];  // broadcast read
            const v2f* zp = (const v2f*)&zf;
#pragma unroll
            for (int j = 0; j < 4; ++j) {
              const v2f* cp = (const v2f*)&cf[j];
              pk_acc(A[i][j][0], pk_mul(zp[0], cp[0]));
              pk_acc(A[i][j][1], pk_mul(zp[1], cp[1]));
            }
          }
        }
      }
    }

    // npyv hadd + dist + first-min (k ascending per thread within this block)
#pragma unroll
    for (int j = 0; j < 4; ++j) {
      const int k = kt * 64 + tk + 16 * j;
      const float cq = cbsqb[k];
#pragma unroll
      for (int i = 0; i < 8; ++i) {
        float dot = (A[i][j][0].x + A[i][j][0].y) + (A[i][j][1].x + A[i][j][1].y);
        float dist = (zsqv[i] - 2.0f * dot) + cq;  // 2*dot exact (pow2 mul)
        if (dist < m[i]) { m[i] = dist; bi[i] = k; }
      }
    }
  }

  // lex-min (value, index) across the 16 tk-lanes sharing each n, then merge
  // across kt-split blocks via order-preserving packed atomicMin.
#pragma unroll
  for (int i = 0; i < 8; ++i) {
#pragma unroll
    for (int off = 8; off >= 1; off >>= 1) {
      float om = __shfl_xor(m[i], off);
      int oi = __shfl_xor(bi[i], off);
      if (om < m[i] || (om == m[i] && oi < bi[i])) { m[i] = om; bi[i] = oi; }
    }
  }
  if (tk == 0) {
#pragma unroll
    for (int i = 0; i < 8; ++i) {
      unsigned uk = __float_as_uint(m[i]);
      uk = (uk & 0x80000000u) ? ~uk : (uk | 0x80000000u);  // order-preserving
      unsigned long long pkd = ((unsigned long long)uk << 32) | (unsigned)bi[i];
      atomicMin(&best[b * NP + n0 + tn + 16 * i], pkd);
    }
  }
}

// ---- gather selected rows -> [B,H,W,D] (bitwise copy; overwrites zT) ----
__global__ __launch_bounds__(256) void vq_gather_kernel(
    const int* __restrict__ c, const float* __restrict__ emb,
    const unsigned long long* __restrict__ best, float* __restrict__ out) {
  int t = threadIdx.x;
  int r = blockIdx.x * 4 + (t >> 6);
  int lane = t & 63;
  int b = r >> 12;
  int k = (int)(unsigned)(best[r] & 0xFFFFFFFFu);
  const float4* src = (const float4*)(emb + (size_t)(c[b] * KC + k) * DD);
  float4* dst = (float4*)(out + (size_t)r * DD);
  dst[lane] = src[lane];
}

extern "C" void kernel_launch(void* const* d_in, const int* in_sizes, int n_in,
                              void* d_out, int out_size, void* d_ws, size_t ws_size,
                              hipStream_t stream) {
  const float* z = (const float*)d_in[0];    // [32,256,64,64]
  const int* c = (const int*)d_in[1];        // [32]
  const float* emb = (const float*)d_in[2];  // [30720,256]
  float* out = (float*)d_out;                // [32,64,64,256]

  char* ws = (char*)d_ws;
  float* zsq = (float*)ws;                                   // 512 KB
  float* cbsq = (float*)(ws + 524288);                       // 120 KB
  unsigned long long* best = (unsigned long long*)(ws + 655360);  // 1 MB

  float* zT = out;  // d_out doubles as zT[b][n][d] scratch; gather overwrites it

  hipMemsetAsync(best, 0xFF, (size_t)BB * NP * 8, stream);
  zprep_kernel<<<BB * (NP / 64), 64, 0, stream>>>(z, zsq, zT);
  cbsq_kernel<<<(NCLS * KC) / 64, 64, 0, stream>>>(emb, cbsq);
  dim3 gA(NP / 128, BB, 2);
  vq_main_kernel<<<gA, 256, 0, stream>>>(zT, c, emb, zsq, cbsq, best);
  vq_gather_kernel<<<(BB * NP) / 4, 256, 0, stream>>>(c, emb, best, out);
}

// Round 9
// 777.723 us; speedup vs baseline: 1.5768x; 1.1695x over previous
//
#include <hip/hip_runtime.h>
#include <cstdint>

#define NCLS 60
#define KC 512
#define DD 256
#define BB 32
#define NP 4096
#define DPAD 68    // LDS row stride (floats): mult-of-4 for b128; conflict-free
#define LDP 260    // row stride for the prep kernels
#define EPS 2e-3f  // fma-vs-np dist divergence window (worst-case ~3e-4)
#define FIX_CAP 16384

typedef float v2f __attribute__((ext_vector_type(2)));

// a = x*y + a, packed fp32 FMA (order-free phase: contraction allowed/wanted)
__device__ __forceinline__ void pk_fma(v2f& a, v2f x, v2f y) {
  asm("v_pk_fma_f32 %0, %1, %2, %0" : "+v"(a) : "v"(x), "v"(y));
}

// Rounded fp32 multiply that cannot fuse into a following add (np-exact path).
__device__ __forceinline__ float mul_rn_nofuse(float a, float b) {
  float p = a * b;
  asm("" : "+v"(p));
  return p;
}

// numpy pairwise_sum of x*x over 256 contiguous floats.
__device__ __forceinline__ float np_pairwise256_sq(const float* row) {
  float h0 = 0.f, h1 = 0.f;
#pragma unroll
  for (int half = 0; half < 2; ++half) {
    const float* a = row + half * 128;
    float r[8];
#pragma unroll
    for (int j = 0; j < 8; ++j) r[j] = mul_rn_nofuse(a[j], a[j]);
    for (int blk = 1; blk < 16; ++blk) {
#pragma unroll
      for (int j = 0; j < 8; ++j) {
        float p = mul_rn_nofuse(a[blk * 8 + j], a[blk * 8 + j]);
        r[j] = r[j] + p;
      }
    }
    float res = ((r[0] + r[1]) + (r[2] + r[3])) + ((r[4] + r[5]) + (r[6] + r[7]));
    if (half == 0) h0 = res; else h1 = res;
  }
  return h0 + h1;
}

// np-einsum SSE-order dot over 256 floats (gold-validated in rounds 3-8):
// 16-chunks ascending, reversed 4-sub-blocks, 4 lane-accs, hadd (a0+a1)+(a2+a3).
__device__ __forceinline__ float np_dot256(const float* __restrict__ zr,
                                           const float* __restrict__ cr) {
  float A0 = 0.f, A1 = 0.f, A2 = 0.f, A3 = 0.f;
#pragma unroll 1
  for (int c16 = 0; c16 < 16; ++c16) {
    const float* zz = zr + c16 * 16;
    const float* cc = cr + c16 * 16;
#pragma unroll
    for (int s = 3; s >= 0; --s) {
      A0 = mul_rn_nofuse(zz[s * 4 + 0], cc[s * 4 + 0]) + A0;
      A1 = mul_rn_nofuse(zz[s * 4 + 1], cc[s * 4 + 1]) + A1;
      A2 = mul_rn_nofuse(zz[s * 4 + 2], cc[s * 4 + 2]) + A2;
      A3 = mul_rn_nofuse(zz[s * 4 + 3], cc[s * 4 + 3]) + A3;
    }
  }
  return (A0 + A1) + (A2 + A3);
}

// ---- prep: z_sq (numpy order) AND global transpose zT[b][n][d] (into d_out) --
__global__ __launch_bounds__(64) void zprep_kernel(const float* __restrict__ z,
                                                   float* __restrict__ zsq,
                                                   float* __restrict__ zT) {
  __shared__ float zs[64][LDP];
  int t = threadIdx.x;
  int b = blockIdx.x >> 6;
  int n0 = (blockIdx.x & 63) * 64;
  const float* zb = z + (size_t)b * DD * NP;
  for (int d = 0; d < DD; ++d) zs[t][d] = zb[(size_t)d * NP + n0 + t];
  __syncthreads();
  zsq[b * NP + n0 + t] = np_pairwise256_sq(&zs[t][0]);
  float* ob = zT + ((size_t)b * NP + n0) * DD;
  for (int it = 0; it < 64; ++it) {
    *(float4*)&ob[(size_t)it * DD + t * 4] = *(const float4*)&zs[it][t * 4];
  }
}

__global__ __launch_bounds__(64) void cbsq_kernel(const float* __restrict__ emb,
                                                  float* __restrict__ cbsq) {
  __shared__ float cs[64][LDP];
  int t = threadIdx.x;
  int r0 = blockIdx.x * 64;
  const float4* e4 = (const float4*)emb;
  for (int rr = 0; rr < 64; ++rr) {
    float4 v = e4[(size_t)(r0 + rr) * 64 + t];
    *(float4*)&cs[rr][t * 4] = v;
  }
  __syncthreads();
  cbsq[r0 + t] = np_pairwise256_sq(&cs[t][0]);
}

// ---- phase 1: FMA dist + top-2 argmin; near-ties flagged for np-exact fixup --
// 8n x 4k micro-tile; zT staged b128->b128 (conflict-free); pk_fma inner loop.
__global__ __launch_bounds__(256) void vq_fma_kernel(
    const float* __restrict__ zT, const int* __restrict__ c,
    const float* __restrict__ emb, const float* __restrict__ zsq,
    const float* __restrict__ cbsq, int* __restrict__ idx_out,
    unsigned int* __restrict__ counter, unsigned int* __restrict__ fixlist) {
  __shared__ __align__(16) float zs[128][DPAD];  // 34.8 KB
  __shared__ __align__(16) float cs[64][DPAD];   // 17.4 KB
  const int t = threadIdx.x;
  const int b = blockIdx.y;
  const int n0 = blockIdx.x * 128;
  const int tn = t >> 4, tk = t & 15;
  const int cls = c[b];
  const float* __restrict__ zTb = zT + ((size_t)b * NP + n0) * DD;
  const float* __restrict__ cbc = emb + (size_t)cls * KC * DD;
  const float* __restrict__ cbsqb = cbsq + cls * KC;

  float zsqv[8];
#pragma unroll
  for (int i = 0; i < 8; ++i) zsqv[i] = zsq[b * NP + n0 + tn + 16 * i];

  float m1[8], m2[8];
  int i1[8];
#pragma unroll
  for (int i = 0; i < 8; ++i) { m1[i] = 3.4e38f; m2[i] = 3.4e38f; i1[i] = 0; }

#pragma unroll 1
  for (int kt = 0; kt < 8; ++kt) {
    const float* __restrict__ cbk = cbc + (size_t)kt * 64 * DD;
    v2f A[8][4][2];
#pragma unroll
    for (int i = 0; i < 8; ++i)
#pragma unroll
      for (int j = 0; j < 4; ++j) {
        A[i][j][0] = (v2f){0.f, 0.f};
        A[i][j][1] = (v2f){0.f, 0.f};
      }

#pragma unroll 1
    for (int dc = 0; dc < 4; ++dc) {
      const int d0g = dc * 64;
      __syncthreads();
#pragma unroll
      for (int it = 0; it < 8; ++it) {
        int f4i = it * 256 + t;
        int row = f4i >> 4, dq = f4i & 15;
        *(float4*)&zs[row][dq * 4] =
            *(const float4*)&zTb[(size_t)row * DD + d0g + dq * 4];
      }
#pragma unroll
      for (int it = 0; it < 4; ++it) {
        int f4i = it * 256 + t;
        int kr = f4i >> 4, dq = f4i & 15;
        *(float4*)&cs[kr][dq * 4] =
            *(const float4*)&cbk[(size_t)kr * DD + d0g + dq * 4];
      }
      __syncthreads();

#pragma unroll 1
      for (int d16 = 0; d16 < 4; ++d16) {
#pragma unroll
        for (int dq = 0; dq < 4; ++dq) {
          const int d0 = d16 * 16 + dq * 4;
          float4 cf[4];
#pragma unroll
          for (int j = 0; j < 4; ++j) cf[j] = *(const float4*)&cs[tk + 16 * j][d0];
#pragma unroll
          for (int i = 0; i < 8; ++i) {
            float4 zf = *(const float4*)&zs[tn + 16 * i][d0];  // broadcast read
            const v2f* zp = (const v2f*)&zf;
#pragma unroll
            for (int j = 0; j < 4; ++j) {
              const v2f* cp = (const v2f*)&cf[j];
              pk_fma(A[i][j][0], zp[0], cp[0]);
              pk_fma(A[i][j][1], zp[1], cp[1]);
            }
          }
        }
      }
    }

    // dist + top-2 (k strictly ascending per thread)
#pragma unroll
    for (int j = 0; j < 4; ++j) {
      const int k = kt * 64 + tk + 16 * j;
      const float cq = cbsqb[k];
#pragma unroll
      for (int i = 0; i < 8; ++i) {
        float dot = (A[i][j][0].x + A[i][j][0].y) + (A[i][j][1].x + A[i][j][1].y);
        float dist = (zsqv[i] - 2.0f * dot) + cq;
        if (dist < m1[i]) {
          m2[i] = m1[i]; m1[i] = dist; i1[i] = k;
        } else if (dist < m2[i]) {
          m2[i] = dist;
        }
      }
    }
  }

  // top-2 butterfly across the 16 tk-lanes sharing each n
#pragma unroll
  for (int i = 0; i < 8; ++i) {
#pragma unroll
    for (int off = 8; off >= 1; off >>= 1) {
      float om1 = __shfl_xor(m1[i], off);
      float om2 = __shfl_xor(m2[i], off);
      int oi = __shfl_xor(i1[i], off);
      bool take = (om1 < m1[i]) || (om1 == m1[i] && oi < i1[i]);
      if (take) {
        m2[i] = fminf(m1[i], om2);
        m1[i] = om1;
        i1[i] = oi;
      } else {
        m2[i] = fminf(m2[i], om1);
      }
    }
  }
  if (tk == 0) {
#pragma unroll
    for (int i = 0; i < 8; ++i) {
      int n = n0 + tn + 16 * i;
      idx_out[b * NP + n] = i1[i];
      if (m2[i] - m1[i] < EPS) {  // near-tie under fma-vs-np divergence bound
        unsigned p = atomicAdd(counter, 1u);
        if (p < FIX_CAP) fixlist[p] = ((unsigned)b << 12) | (unsigned)n;
      }
    }
  }
}

// ---- phase 2: np-exact re-resolution (full 512 k) of flagged positions ----
__global__ __launch_bounds__(256) void vq_fix_kernel(
    const float* __restrict__ zT, const int* __restrict__ c,
    const float* __restrict__ emb, const float* __restrict__ zsq,
    const float* __restrict__ cbsq, int* __restrict__ idx_out,
    const unsigned int* __restrict__ counter,
    const unsigned int* __restrict__ fixlist) {
  unsigned cnt = *counter;
  if (cnt > FIX_CAP) cnt = FIX_CAP;
  if (blockIdx.x >= cnt) return;
  unsigned packed = fixlist[blockIdx.x];
  int b = (int)(packed >> 12);
  int n = (int)(packed & (NP - 1));
  int t = threadIdx.x;

  __shared__ __align__(16) float zrow[DD];
  if (t < 64) *(float4*)&zrow[t * 4] = *(const float4*)&zT[((size_t)b * NP + n) * DD + t * 4];
  __syncthreads();

  const int cls = c[b];
  const float zsq_n = zsq[b * NP + n];
  const float* cbc = emb + (size_t)cls * KC * DD;

  float best = 3.4e38f;
  int bk = 0;
#pragma unroll
  for (int kk = 0; kk < 2; ++kk) {
    int k = t + kk * 256;  // ascending per thread
    float dot = np_dot256(zrow, cbc + (size_t)k * DD);
    float dist = (zsq_n - 2.0f * dot) + cbsq[cls * KC + k];
    if (dist < best) { best = dist; bk = k; }  // k ascending -> first-min
  }

  __shared__ float rb[256];
  __shared__ int ri[256];
  rb[t] = best;
  ri[t] = bk;
  __syncthreads();
  for (int off = 128; off >= 1; off >>= 1) {
    if (t < off) {
      float ob = rb[t + off];
      int oi = ri[t + off];
      if (ob < rb[t] || (ob == rb[t] && oi < ri[t])) { rb[t] = ob; ri[t] = oi; }
    }
    __syncthreads();
  }
  if (t == 0) idx_out[b * NP + n] = ri[0];
}

// ---- gather selected rows -> [B,H,W,D] (bitwise copy; overwrites zT) ----
__global__ __launch_bounds__(256) void vq_gather_kernel(
    const int* __restrict__ c, const float* __restrict__ emb,
    const int* __restrict__ idx, float* __restrict__ out) {
  int t = threadIdx.x;
  int r = blockIdx.x * 4 + (t >> 6);
  int lane = t & 63;
  int b = r >> 12;
  int k = idx[r];
  const float4* src = (const float4*)(emb + (size_t)(c[b] * KC + k) * DD);
  float4* dst = (float4*)(out + (size_t)r * DD);
  dst[lane] = src[lane];
}

extern "C" void kernel_launch(void* const* d_in, const int* in_sizes, int n_in,
                              void* d_out, int out_size, void* d_ws, size_t ws_size,
                              hipStream_t stream) {
  const float* z = (const float*)d_in[0];    // [32,256,64,64]
  const int* c = (const int*)d_in[1];        // [32]
  const float* emb = (const float*)d_in[2];  // [30720,256]
  float* out = (float*)d_out;                // [32,64,64,256]

  char* ws = (char*)d_ws;
  float* zsq = (float*)ws;                                 // 512 KB
  float* cbsq = (float*)(ws + 524288);                     // 120 KB
  int* idx = (int*)(ws + 655360);                          // 512 KB
  unsigned int* counter = (unsigned int*)(ws + 1179648);
  unsigned int* fixlist = counter + 1;                     // 64 KB

  float* zT = out;  // d_out doubles as zT[b][n][d]; gather overwrites it last

  hipMemsetAsync(counter, 0, sizeof(unsigned int), stream);
  zprep_kernel<<<BB * (NP / 64), 64, 0, stream>>>(z, zsq, zT);
  cbsq_kernel<<<(NCLS * KC) / 64, 64, 0, stream>>>(emb, cbsq);
  dim3 gA(NP / 128, BB);
  vq_fma_kernel<<<gA, 256, 0, stream>>>(zT, c, emb, zsq, cbsq, idx, counter, fixlist);
  vq_fix_kernel<<<FIX_CAP, 256, 0, stream>>>(zT, c, emb, zsq, cbsq, idx, counter, fixlist);
  vq_gather_kernel<<<(BB * NP) / 4, 256, 0, stream>>>(c, emb, idx, out);
}